// Round 9
// baseline (134.742 us; speedup 1.0000x reference)
//
#include <hip/hip_runtime.h>
#include <hip/hip_bf16.h>
#include <type_traits>

#define D 96
#define LN_EPS 1e-5f
#define CHUNK 1024          // edges per partition block
#define BCAP 4608           // per-bucket capacity in part[] (mean 4096, +8 sigma)
#define BCAPP (BCAP + 7936) // per-bucket region in csr_src (pad-32 slack = 31*256)

typedef unsigned short ushort_t;
typedef __attribute__((ext_vector_type(8))) short short8;
typedef __attribute__((ext_vector_type(4))) float f32x4;

__device__ __forceinline__ ushort_t f2bf(float f) {
    unsigned u = __float_as_uint(f);
    u += 0x7FFF + ((u >> 16) & 1);          // round-to-nearest-even
    return (ushort_t)(u >> 16);
}
__device__ __forceinline__ float blo(unsigned v) {   // low bf16 -> f32
    return __uint_as_float(v << 16);
}
__device__ __forceinline__ float bhi(unsigned v) {   // high bf16 -> f32
    return __uint_as_float(v & 0xffff0000u);
}

// ---------------------------------------------------------------------------
// Init (block 0): edge dtype detect + gcur = b*BCAP + zero hs sentinel rows.
// Blocks 1..72: W0,W1 (f32 [k][c]) -> Wt0,Wt1 (bf16 transposed [c][k]).
// ---------------------------------------------------------------------------
__global__ __launch_bounds__(256) void k_init(const unsigned* __restrict__ w,
                                              int* __restrict__ flag,
                                              int* __restrict__ gcur,
                                              unsigned* __restrict__ hsA,
                                              unsigned* __restrict__ hsB, int N,
                                              int nbuk,
                                              const float* __restrict__ W0,
                                              const float* __restrict__ W1,
                                              ushort_t* __restrict__ Wt0,
                                              ushort_t* __restrict__ Wt1) {
    int t = threadIdx.x;
    if (blockIdx.x == 0) {
        __shared__ int anynz;
        if (t == 0) anynz = 0;
        __syncthreads();
        if ((t & 1) && w[t] != 0) anynz = 1;
        if (t < nbuk) gcur[t] = t * BCAP;
        if (t < 32) hsA[(size_t)N * 32 + t] = 0;   // sentinel row
        if (t < 16) hsB[(size_t)N * 16 + t] = 0;
        __syncthreads();
        if (t == 0) *flag = (anynz == 0) ? 1 : 0;
    } else {
        int idx = (blockIdx.x - 1) * 256 + t;   // < 18432
        int sel = idx / 9216, i = idx % 9216;
        int c = i / 96, k = i % 96;
        const float* W = sel ? W1 : W0;
        ushort_t* Wt = sel ? Wt1 : Wt0;
        Wt[c * 96 + k] = f2bf(W[k * 96 + c]);
    }
}

__device__ __forceinline__ int load_idx(const void* eb, int is64, long long pos) {
    if (is64) return (int)((const long long*)eb)[pos];
    return ((const int*)eb)[pos];
}

// ---------------------------------------------------------------------------
// Partition edges into fixed-capacity bucket regions (bucket = dst >> 8).
// Duplicated LDS hist/cursors (per wave-pair) halve same-bin serialization.
// ---------------------------------------------------------------------------
__global__ __launch_bounds__(256) void k_bfill(const void* __restrict__ eb,
                                               const int* __restrict__ flag,
                                               int* __restrict__ gcur,
                                               unsigned* __restrict__ part, int E) {
    __shared__ int hist[2][256];
    __shared__ int cur[2][256];
    int t = threadIdx.x;
    int half = t >> 7;
    hist[0][t] = 0; hist[1][t] = 0;
    __syncthreads();
    int is64 = *flag;
    long long base = (long long)blockIdx.x * CHUNK;
    int sv[CHUNK / 256];
    int dv[CHUNK / 256];
    #pragma unroll
    for (int i = 0; i < CHUNK / 256; ++i) {
        long long e = base + t + (long long)i * 256;
        if (e < E) {
            sv[i] = load_idx(eb, is64, e);
            dv[i] = load_idx(eb, is64, (long long)E + e);
            atomicAdd(&hist[half][dv[i] >> 8], 1);
        } else dv[i] = -1;
    }
    __syncthreads();
    int h0 = hist[0][t], tot = h0 + hist[1][t];
    int b0 = 0;
    if (tot > 0) b0 = atomicAdd(&gcur[t], tot);
    cur[0][t] = b0;
    cur[1][t] = b0 + h0;
    __syncthreads();
    #pragma unroll
    for (int i = 0; i < CHUNK / 256; ++i) {
        if (dv[i] >= 0) {
            int b = dv[i] >> 8;
            int pos = atomicAdd(&cur[half][b], 1);
            part[pos] = ((unsigned)sv[i] << 8) | (unsigned)(dv[i] & 255);
        }
    }
}

// ---------------------------------------------------------------------------
// Per-bucket CSR finalize, per-node padding to multiple of 32 (sentinel = N),
// so the agg inner loop is a fully-static 4-burst pipeline.
// Bucket b: part region [b*BCAP, gcur[b]); csr region starts at b*BCAPP.
// ---------------------------------------------------------------------------
__global__ __launch_bounds__(256) void k_build(const unsigned* __restrict__ part,
                                               const int* __restrict__ gcur,
                                               int2* __restrict__ rr,
                                               int* __restrict__ csr_src,
                                               float* __restrict__ dis,
                                               int N) {
    __shared__ int bins[2][256];
    __shared__ int cur[2][256];
    __shared__ int sh[256];
    int t = threadIdx.x;
    int b = blockIdx.x;
    int half = t >> 7;
    int beg = b * BCAP, end = gcur[b];
    bins[0][t] = 0; bins[1][t] = 0;
    __syncthreads();
    for (int i = beg + t; i < end; i += 256)
        atomicAdd(&bins[half][part[i] & 255u], 1);
    __syncthreads();
    int d0 = bins[0][t];
    int deg = d0 + bins[1][t];
    int pdeg = (deg + 31) & ~31;          // pad to x32 for static agg pipeline
    sh[t] = pdeg;
    __syncthreads();
    for (int off = 1; off < 256; off <<= 1) {
        int x = (t >= off) ? sh[t - off] : 0;
        __syncthreads();
        sh[t] += x;
        __syncthreads();
    }
    int mybeg = b * BCAPP + (sh[t] - pdeg);
    int node = b * 256 + t;
    if (node < N) {
        rr[node] = make_int2(mybeg, mybeg + pdeg);
        dis[node] = rsqrtf((float)(deg + 1));
    }
    cur[0][t] = mybeg;
    cur[1][t] = mybeg + d0;
    __syncthreads();
    for (int i = beg + t; i < end; i += 256) {
        unsigned p = part[i];
        int pos = atomicAdd(&cur[half][p & 255u], 1);
        csr_src[pos] = (int)(p >> 8);
    }
    for (int k = deg; k < pdeg; ++k) csr_src[mybeg + k] = N;  // sentinels
}

// ---------------------------------------------------------------------------
// MFMA GEMM: (HsA,HsB)[row] = bf16( dis[row] * (A[N,96] @ W[96,96]) ).
// A: f32 contiguous (layer 1, converted while staging) or split bf16
// (A0=[N][64], A1=[N][32], layer 2). Wt bf16 transposed. 64 rows/block,
// 4 waves, 16 rows/wave. mfma_f32_16x16x32_bf16, m89-verified C/D layout.
// LDS rows padded to 104 elems (208B) -> 2-way conflicts only (free).
// ---------------------------------------------------------------------------
template<typename T>
__global__ __launch_bounds__(256) void k_gemm_mfma(const T* __restrict__ A0,
                                                   const T* __restrict__ A1,
                                                   const ushort_t* __restrict__ Wt,
                                                   const float* __restrict__ dis,
                                                   ushort_t* __restrict__ HsA,
                                                   ushort_t* __restrict__ HsB, int N) {
    __shared__ ushort_t As[64][104];
    __shared__ ushort_t Bs[96][104];
    int t = threadIdx.x;
    int row0 = blockIdx.x * 64;

    if constexpr (std::is_same<T, float>::value) {
        const float4* X4 = (const float4*)A0;
        #pragma unroll
        for (int i = 0; i < 6; ++i) {             // 64x24 float4 = 1536 chunks
            int idx = t + i * 256;
            int r = idx / 24, c4 = idx % 24;
            float4 v = make_float4(0.f, 0.f, 0.f, 0.f);
            if (row0 + r < N) v = X4[(size_t)(row0 + r) * 24 + c4];
            ushort4 o;
            o.x = f2bf(v.x); o.y = f2bf(v.y); o.z = f2bf(v.z); o.w = f2bf(v.w);
            *(ushort4*)&As[r][c4 * 4] = o;
        }
    } else {
        #pragma unroll
        for (int i = 0; i < 3; ++i) {             // 64x12 short8 = 768 chunks
            int idx = t + i * 256;
            int r = idx / 12, c8 = idx % 12;
            short8 v = {0, 0, 0, 0, 0, 0, 0, 0};
            if (row0 + r < N) {
                if (c8 < 8) v = *(const short8*)(A0 + (size_t)(row0 + r) * 64 + c8 * 8);
                else        v = *(const short8*)(A1 + (size_t)(row0 + r) * 32 + (c8 - 8) * 8);
            }
            *(short8*)&As[r][c8 * 8] = v;
        }
    }
    #pragma unroll
    for (int i = 0; i < 5; ++i) {                 // 96x12 short8 = 1152 chunks
        int idx = t + i * 256;
        if (idx < 1152) {
            int r = idx / 12, c8 = idx % 12;
            *(short8*)&Bs[r][c8 * 8] = *(const short8*)(Wt + r * 96 + c8 * 8);
        }
    }
    __syncthreads();

    int w = t >> 6, l = t & 63;
    int lr = l & 15, lq = l >> 4;
    f32x4 acc[6];
    #pragma unroll
    for (int c = 0; c < 6; ++c) acc[c] = (f32x4){0.f, 0.f, 0.f, 0.f};

    #pragma unroll
    for (int q = 0; q < 3; ++q) {
        short8 af = *(const short8*)&As[w * 16 + lr][q * 32 + lq * 8];
        #pragma unroll
        for (int c = 0; c < 6; ++c) {
            short8 bf = *(const short8*)&Bs[c * 16 + lr][q * 32 + lq * 8];
            acc[c] = __builtin_amdgcn_mfma_f32_16x16x32_bf16(af, bf, acc[c], 0, 0, 0);
        }
    }

    int rbase = row0 + w * 16 + lq * 4;
    #pragma unroll
    for (int r = 0; r < 4; ++r) {
        int gr = rbase + r;
        if (gr < N) {
            float dr = dis[gr];
            ushort_t* oA = HsA + (size_t)gr * 64 + lr;
            ushort_t* oB = HsB + (size_t)gr * 32 + lr;
            #pragma unroll
            for (int c = 0; c < 4; ++c) oA[c * 16] = f2bf(dr * acc[c][r]);
            #pragma unroll
            for (int c = 4; c < 6; ++c) oB[(c - 4) * 16] = f2bf(dr * acc[c][r]);
        }
    }
}

// ---------------------------------------------------------------------------
// Fused aggregate + bias + tanh + LayerNorm + affine; split-hs gathers.
// 32-lane group per node; lane l owns features {2l,2l+1} (hsA); hsB is
// gathered two-edges-per-load (lanes 0-15 edge j, 16-31 edge j+1), folded
// by shfl_xor(16). Runs padded to x32 with sentinel row N (zeros, L1-hot)
// -> chunk body is a fully-static 4-burst pipeline (~48 loads in flight).
// ---------------------------------------------------------------------------
template<bool BF16OUT>
__global__ __launch_bounds__(256) void k_agg_ln(const unsigned* __restrict__ hA32,
                                                const unsigned* __restrict__ hB32,
                                                const int2* __restrict__ rr,
                                                const int* __restrict__ csr_src,
                                                const float* __restrict__ dis,
                                                const float* __restrict__ b,
                                                const float* __restrict__ g,
                                                const float* __restrict__ be,
                                                void* __restrict__ outA,
                                                void* __restrict__ outB, int N) {
    int node = blockIdx.x * 8 + (threadIdx.x >> 5);
    int lane = threadIdx.x & 31;
    if (node >= N) return;

    float a0, a1, c0 = 0.f, c1 = 0.f;
    {
        unsigned v = hA32[(size_t)node * 32 + lane];
        a0 = blo(v); a1 = bhi(v);
        if (lane < 16) {
            unsigned uu = hB32[(size_t)node * 16 + lane];
            c0 = blo(uu); c1 = bhi(uu);
        }
    }

    int2 r = rr[node];
    int beg = r.x, end = r.y;       // end - beg is a multiple of 32
    int lsel = lane >> 4;
    int lb = lane & 15;
    for (int cb = beg; cb < end; cb += 32) {
        int sreg = csr_src[cb + lane];       // always valid (padded)
        #pragma unroll
        for (int j = 0; j < 32; j += 8) {
            int s0 = __shfl(sreg, j, 32);
            int s1 = __shfl(sreg, j + 1, 32);
            int s2 = __shfl(sreg, j + 2, 32);
            int s3 = __shfl(sreg, j + 3, 32);
            int s4 = __shfl(sreg, j + 4, 32);
            int s5 = __shfl(sreg, j + 5, 32);
            int s6 = __shfl(sreg, j + 6, 32);
            int s7 = __shfl(sreg, j + 7, 32);
            int p0 = __shfl(sreg, j + lsel, 32);
            int p1 = __shfl(sreg, j + 2 + lsel, 32);
            int p2 = __shfl(sreg, j + 4 + lsel, 32);
            int p3 = __shfl(sreg, j + 6 + lsel, 32);
            unsigned v0 = hA32[s0 * 32 + lane];
            unsigned v1 = hA32[s1 * 32 + lane];
            unsigned v2 = hA32[s2 * 32 + lane];
            unsigned v3 = hA32[s3 * 32 + lane];
            unsigned v4 = hA32[s4 * 32 + lane];
            unsigned v5 = hA32[s5 * 32 + lane];
            unsigned v6 = hA32[s6 * 32 + lane];
            unsigned v7 = hA32[s7 * 32 + lane];
            unsigned w0 = hB32[p0 * 16 + lb];
            unsigned w1 = hB32[p1 * 16 + lb];
            unsigned w2 = hB32[p2 * 16 + lb];
            unsigned w3 = hB32[p3 * 16 + lb];
            a0 += blo(v0) + blo(v1) + blo(v2) + blo(v3)
                + blo(v4) + blo(v5) + blo(v6) + blo(v7);
            a1 += bhi(v0) + bhi(v1) + bhi(v2) + bhi(v3)
                + bhi(v4) + bhi(v5) + bhi(v6) + bhi(v7);
            c0 += blo(w0) + blo(w1) + blo(w2) + blo(w3);
            c1 += bhi(w0) + bhi(w1) + bhi(w2) + bhi(w3);
        }
    }

    c0 += __shfl_xor(c0, 16, 32);
    c1 += __shfl_xor(c1, 16, 32);

    float dn = dis[node];
    float2 b01 = ((const float2*)b)[lane];
    a0 = tanhf(fmaf(dn, a0, b01.x));
    a1 = tanhf(fmaf(dn, a1, b01.y));
    float s1 = a0 + a1;
    float s2 = a0 * a0 + a1 * a1;
    float a2 = 0.f, a3 = 0.f;
    if (lane < 16) {
        float2 b23 = ((const float2*)b)[32 + lane];
        a2 = tanhf(fmaf(dn, c0, b23.x));
        a3 = tanhf(fmaf(dn, c1, b23.y));
        s1 += a2 + a3;
        s2 += a2 * a2 + a3 * a3;
    }
    #pragma unroll
    for (int off = 16; off >= 1; off >>= 1) {
        s1 += __shfl_xor(s1, off, 32);
        s2 += __shfl_xor(s2, off, 32);
    }
    float mu = s1 * (1.f / 96.f);
    float var = s2 * (1.f / 96.f) - mu * mu;
    float inv = rsqrtf(var + LN_EPS);

    float2 g01 = ((const float2*)g)[lane];
    float2 e01 = ((const float2*)be)[lane];
    float r0 = (a0 - mu) * inv * g01.x + e01.x;
    float r1 = (a1 - mu) * inv * g01.y + e01.y;
    if (BF16OUT) {
        ((unsigned*)outA)[(size_t)node * 32 + lane] =
            ((unsigned)f2bf(r1) << 16) | (unsigned)f2bf(r0);
        if (lane < 16) {
            float2 g23 = ((const float2*)g)[32 + lane];
            float2 e23 = ((const float2*)be)[32 + lane];
            float r2 = (a2 - mu) * inv * g23.x + e23.x;
            float r3 = (a3 - mu) * inv * g23.y + e23.y;
            ((unsigned*)outB)[(size_t)node * 16 + lane] =
                ((unsigned)f2bf(r3) << 16) | (unsigned)f2bf(r2);
        }
    } else {
        float2* o2 = (float2*)((float*)outA + (size_t)node * D);
        o2[lane] = make_float2(r0, r1);
        if (lane < 16) {
            float2 g23 = ((const float2*)g)[32 + lane];
            float2 e23 = ((const float2*)be)[32 + lane];
            o2[32 + lane] = make_float2((a2 - mu) * inv * g23.x + e23.x,
                                        (a3 - mu) * inv * g23.y + e23.y);
        }
    }
}

// ---------------------------------------------------------------------------
extern "C" void kernel_launch(void* const* d_in, const int* in_sizes, int n_in,
                              void* d_out, int out_size, void* d_ws, size_t ws_size,
                              hipStream_t stream) {
    const float* x  = (const float*)d_in[0];
    const void*  eb = d_in[1];
    const float* W0 = (const float*)d_in[2];
    const float* b0 = (const float*)d_in[3];
    const float* g0 = (const float*)d_in[4];
    const float* be0 = (const float*)d_in[5];
    const float* W1 = (const float*)d_in[6];
    const float* b1 = (const float*)d_in[7];
    const float* g1 = (const float*)d_in[8];
    const float* be1 = (const float*)d_in[9];

    const int N = in_sizes[0] / D;
    const int E = in_sizes[1] / 2;
    const int NBUK = (N + 255) >> 8;
    const int NBLK = (E + CHUNK - 1) / CHUNK;

    auto al = [](size_t v) { return (v + 255) & ~(size_t)255; };
    char* w = (char*)d_ws;
    size_t off = 0;
    int* flag = (int*)(w + off);          off = al(off + 4);
    int* gcur = (int*)(w + off);          off = al(off + 256 * 4);
    int2* rr = (int2*)(w + off);          off = al(off + (size_t)N * 8);
    float* dis = (float*)(w + off);       off = al(off + (size_t)N * 4);
    int* csr_src = (int*)(w + off);       off = al(off + ((size_t)NBUK * BCAPP + 64) * 4);
    unsigned* part = (unsigned*)(w + off); off = al(off + ((size_t)NBUK * BCAP + BCAP) * 4);
    unsigned* hsA = (unsigned*)(w + off); off = al(off + ((size_t)N + 1) * 128);
    unsigned* hsB = (unsigned*)(w + off); off = al(off + ((size_t)N + 1) * 64);
    unsigned* h1A = (unsigned*)(w + off); off = al(off + (size_t)N * 128);
    unsigned* h1B = (unsigned*)(w + off); off = al(off + (size_t)N * 64);
    ushort_t* Wt0 = (ushort_t*)(w + off); off = al(off + 9216 * 2);
    ushort_t* Wt1 = (ushort_t*)(w + off); off = al(off + 9216 * 2);
    float* outf = (float*)d_out;

    const int nbG = (N + 63) / 64;
    const int nbA = (N + 7) / 8;

    k_init<<<73, 256, 0, stream>>>((const unsigned*)eb, flag, gcur, hsA, hsB, N,
                                   NBUK, W0, W1, Wt0, Wt1);
    k_bfill<<<NBLK, 256, 0, stream>>>(eb, flag, gcur, part, E);
    k_build<<<NBUK, 256, 0, stream>>>(part, gcur, rr, csr_src, dis, N);

    // Layer 1: MFMA GEMM (f32 in, converts while staging) -> hsA/hsB ; agg -> h1A/h1B
    k_gemm_mfma<float><<<nbG, 256, 0, stream>>>(x, (const float*)nullptr, Wt0, dis,
                                                (ushort_t*)hsA, (ushort_t*)hsB, N);
    k_agg_ln<true><<<nbA, 256, 0, stream>>>(hsA, hsB, rr, csr_src, dis,
                                            b0, g0, be0, (void*)h1A, (void*)h1B, N);
    // Layer 2: MFMA GEMM (split bf16 in) -> hsA/hsB ; agg -> d_out (f32)
    k_gemm_mfma<ushort_t><<<nbG, 256, 0, stream>>>((const ushort_t*)h1A,
                                                   (const ushort_t*)h1B, Wt1, dis,
                                                   (ushort_t*)hsA, (ushort_t*)hsB, N);
    k_agg_ln<false><<<nbA, 256, 0, stream>>>(hsA, hsB, rr, csr_src, dis,
                                             b1, g1, be1, (void*)outf, nullptr, N);
}

// Round 10
// 126.867 us; speedup vs baseline: 1.0621x; 1.0621x over previous
//
#include <hip/hip_runtime.h>
#include <hip/hip_bf16.h>
#include <type_traits>

#define D 96
#define LN_EPS 1e-5f
#define CHUNK 1024          // edges per partition block
#define BCAP 8192           // per-bucket fixed capacity in part[] (mean 4096)
#define BCAPP (BCAP + 1792) // per-bucket region in csr_src (pad-8 slack = 7*256)

typedef unsigned short ushort_t;
typedef __attribute__((ext_vector_type(8))) short short8;
typedef __attribute__((ext_vector_type(4))) float f32x4;

__device__ __forceinline__ ushort_t f2bf(float f) {
    unsigned u = __float_as_uint(f);
    u += 0x7FFF + ((u >> 16) & 1);          // round-to-nearest-even
    return (ushort_t)(u >> 16);
}
__device__ __forceinline__ float blo(unsigned v) {   // low bf16 -> f32
    return __uint_as_float(v << 16);
}
__device__ __forceinline__ float bhi(unsigned v) {   // high bf16 -> f32
    return __uint_as_float(v & 0xffff0000u);
}

__device__ __forceinline__ int load_idx(const void* eb, int is64, long long pos) {
    if (is64) return (int)((const long long*)eb)[pos];
    return ((const int*)eb)[pos];
}

// ---------------------------------------------------------------------------
// MFMA GEMM: (HsA,HsB)[row] = bf16( dis[row] * (A @ W) ). A: f32 (layer 1,
// converted while staging; dis=nullptr -> no scale... layer1 uses dis) or
// split bf16 (A0=[N][64], A1=[N][32], layer 2). W is f32 row-major [k][c],
// transpose-converted to bf16 during LDS staging. 64 rows/block, 4 waves.
// mfma_f32_16x16x32_bf16: A[row=l&15][k=(l>>4)*8+j], B[k][col=l&15],
// D[row=(l>>4)*4+reg][col=l&15] (m89-verified). LDS rows padded to 104
// elems (208B) -> 2-way conflicts only (free).
// INIT: block 0 additionally initializes gcur and the hs sentinel rows
// (must be the first kernel of the call).
// ---------------------------------------------------------------------------
template<typename T, bool INIT>
__global__ __launch_bounds__(256) void k_gemm_mfma(const T* __restrict__ A0,
                                                   const T* __restrict__ A1,
                                                   const float* __restrict__ W,
                                                   const float* __restrict__ dis,
                                                   ushort_t* __restrict__ HsA,
                                                   ushort_t* __restrict__ HsB, int N,
                                                   int* __restrict__ gcur, int nbuk) {
    __shared__ ushort_t As[64][104];
    __shared__ ushort_t Bs[96][104];
    int t = threadIdx.x;
    int row0 = blockIdx.x * 64;

    if constexpr (INIT) {
        if (blockIdx.x == 0) {
            if (t < nbuk) gcur[t] = t * BCAP;
            if (t < 32) ((unsigned*)HsA)[(size_t)N * 32 + t] = 0;  // sentinel
            if (t < 16) ((unsigned*)HsB)[(size_t)N * 16 + t] = 0;
        }
    }

    if constexpr (std::is_same<T, float>::value) {
        const float4* X4 = (const float4*)A0;
        #pragma unroll
        for (int i = 0; i < 6; ++i) {             // 64x24 float4 = 1536 chunks
            int idx = t + i * 256;
            int r = idx / 24, c4 = idx % 24;
            float4 v = make_float4(0.f, 0.f, 0.f, 0.f);
            if (row0 + r < N) v = X4[(size_t)(row0 + r) * 24 + c4];
            ushort4 o;
            o.x = f2bf(v.x); o.y = f2bf(v.y); o.z = f2bf(v.z); o.w = f2bf(v.w);
            *(ushort4*)&As[r][c4 * 4] = o;
        }
    } else {
        #pragma unroll
        for (int i = 0; i < 3; ++i) {             // 64x12 short8 = 768 chunks
            int idx = t + i * 256;
            int r = idx / 12, c8 = idx % 12;
            short8 v = {0, 0, 0, 0, 0, 0, 0, 0};
            if (row0 + r < N) {
                if (c8 < 8) v = *(const short8*)(A0 + (size_t)(row0 + r) * 64 + c8 * 8);
                else        v = *(const short8*)(A1 + (size_t)(row0 + r) * 32 + (c8 - 8) * 8);
            }
            *(short8*)&As[r][c8 * 8] = v;
        }
    }
    // W: f32 [k][c] -> Bs[c][k] bf16 (transpose-convert during staging)
    const float4* W4 = (const float4*)W;
    #pragma unroll
    for (int i = 0; i < 9; ++i) {                 // 96x24 float4 = 2304 chunks
        int idx = t + i * 256;
        int k = idx / 24, c4 = idx % 24;
        float4 v = W4[idx];
        Bs[c4 * 4 + 0][k] = f2bf(v.x);
        Bs[c4 * 4 + 1][k] = f2bf(v.y);
        Bs[c4 * 4 + 2][k] = f2bf(v.z);
        Bs[c4 * 4 + 3][k] = f2bf(v.w);
    }
    __syncthreads();

    int w = t >> 6, l = t & 63;
    int lr = l & 15, lq = l >> 4;
    f32x4 acc[6];
    #pragma unroll
    for (int c = 0; c < 6; ++c) acc[c] = (f32x4){0.f, 0.f, 0.f, 0.f};

    #pragma unroll
    for (int q = 0; q < 3; ++q) {
        short8 af = *(const short8*)&As[w * 16 + lr][q * 32 + lq * 8];
        #pragma unroll
        for (int c = 0; c < 6; ++c) {
            short8 bf = *(const short8*)&Bs[c * 16 + lr][q * 32 + lq * 8];
            acc[c] = __builtin_amdgcn_mfma_f32_16x16x32_bf16(af, bf, acc[c], 0, 0, 0);
        }
    }

    int rbase = row0 + w * 16 + lq * 4;
    #pragma unroll
    for (int r = 0; r < 4; ++r) {
        int gr = rbase + r;
        if (gr < N) {
            float dr = dis[gr];
            ushort_t* oA = HsA + (size_t)gr * 64 + lr;
            ushort_t* oB = HsB + (size_t)gr * 32 + lr;
            #pragma unroll
            for (int c = 0; c < 4; ++c) oA[c * 16] = f2bf(dr * acc[c][r]);
            #pragma unroll
            for (int c = 4; c < 6; ++c) oB[(c - 4) * 16] = f2bf(dr * acc[c][r]);
        }
    }
}

// Layer-1 GEMM needs dis before k_build computes it... it does NOT: layer-1
// output scale uses dis computed by k_build, but gemm1 runs BEFORE build in
// this schedule. Solution (as in R7): gemm1 writes UNSCALED... no — R7 ran
// build before gemm1. Here gemm1 runs first for the INIT embedding, so gemm1
// must not read dis. Use a constant-1 path instead: dis==nullptr -> scale 1,
// and fold dis into k_build's... that re-adds traffic. Simpler: keep R7
// order (bfill, build, THEN gemms) and put INIT in bfill's... bfill needs
// gcur already initialized. Final resolution: dedicated tiny init inside
// k_bfill block 0 is impossible (ordering), so keep gemm1 first but scale
// by dis inside k_agg_ln instead (agg multiplies the self term and the
// neighbor sum by dis anyway AFTER summation: a = dn * (sum of dis-scaled
// rows)). With unscaled hs rows we need per-source dis — NOT available
// cheaply. Therefore: run k_build BEFORE gemm1 (R7 order) and do INIT in a
// 1-block prologue merged into bfill via a grid-wide trick — not possible.
// => keep a minimal 1-block k_init (detect-free, ~1-2us).

__global__ __launch_bounds__(256) void k_init(int* __restrict__ gcur,
                                              unsigned* __restrict__ hsA,
                                              unsigned* __restrict__ hsB,
                                              int N, int nbuk) {
    int t = threadIdx.x;
    if (t < nbuk) gcur[t] = t * BCAP;
    if (t < 32) hsA[(size_t)N * 32 + t] = 0;
    if (t < 16) hsB[(size_t)N * 16 + t] = 0;
}

// ---------------------------------------------------------------------------
// Partition edges into fixed-capacity bucket regions (bucket = dst >> 8)
// with BLOCK-LOCAL COUNTING SORT so global part[] writes are coalesced
// (bucket runs of ~5 entries written contiguously instead of 1-per-line).
// Edge dtype detected per block from the first 1 KiB (L2-hot).
// ---------------------------------------------------------------------------
__global__ __launch_bounds__(256) void k_bfill(const void* __restrict__ eb,
                                               int* __restrict__ gcur,
                                               unsigned* __restrict__ part, int E) {
    __shared__ int hist[2][256];
    __shared__ int lcur[2][256];
    __shared__ int sh[256];
    __shared__ int loc[256];
    __shared__ int gbase[256];
    __shared__ unsigned sorted[CHUNK];
    __shared__ unsigned char bkt[CHUNK];
    __shared__ int anynz;
    __shared__ int totsum;
    int t = threadIdx.x;
    int half = t >> 7;

    if (t == 0) anynz = 0;
    hist[0][t] = 0; hist[1][t] = 0;
    __syncthreads();
    if ((t & 1) && ((const unsigned*)eb)[t] != 0) anynz = 1;
    __syncthreads();
    int is64 = (anynz == 0) ? 1 : 0;

    long long base = (long long)blockIdx.x * CHUNK;
    int sv[CHUNK / 256];
    int dv[CHUNK / 256];
    #pragma unroll
    for (int i = 0; i < CHUNK / 256; ++i) {
        long long e = base + t + (long long)i * 256;
        if (e < E) {
            sv[i] = load_idx(eb, is64, e);
            dv[i] = load_idx(eb, is64, (long long)E + e);
            atomicAdd(&hist[half][dv[i] >> 8], 1);
        } else dv[i] = -1;
    }
    __syncthreads();
    int h0 = hist[0][t], tot = h0 + hist[1][t];
    int gb = 0;
    if (tot > 0) gb = atomicAdd(&gcur[t], tot);
    gbase[t] = gb;
    sh[t] = tot;
    __syncthreads();
    for (int off = 1; off < 256; off <<= 1) {
        int x = (t >= off) ? sh[t - off] : 0;
        __syncthreads();
        sh[t] += x;
        __syncthreads();
    }
    int excl = sh[t] - tot;
    loc[t] = excl;
    lcur[0][t] = excl;
    lcur[1][t] = excl + h0;
    if (t == 255) totsum = sh[255];
    __syncthreads();
    // scatter into LDS, bucket-sorted
    #pragma unroll
    for (int i = 0; i < CHUNK / 256; ++i) {
        if (dv[i] >= 0) {
            int bk = dv[i] >> 8;
            int pos = atomicAdd(&lcur[half][bk], 1);
            sorted[pos] = ((unsigned)sv[i] << 8) | (unsigned)(dv[i] & 255);
            bkt[pos] = (unsigned char)bk;
        }
    }
    __syncthreads();
    // coalesced global writes: consecutive i -> consecutive part[] slots
    int tts = totsum;
    for (int i = t; i < tts; i += 256) {
        int bk = bkt[i];
        part[gbase[bk] + (i - loc[bk])] = sorted[i];
    }
}

// ---------------------------------------------------------------------------
// Per-bucket CSR finalize, per-node padding to multiple of 8 (sentinel = N).
// Bucket b: part region [b*BCAP, gcur[b]); csr region starts at b*BCAPP.
// rr[node] = (rbeg, rend) packed.
// ---------------------------------------------------------------------------
__global__ __launch_bounds__(256) void k_build(const unsigned* __restrict__ part,
                                               const int* __restrict__ gcur,
                                               int2* __restrict__ rr,
                                               int* __restrict__ csr_src,
                                               float* __restrict__ dis,
                                               int N) {
    __shared__ int bins[2][256];
    __shared__ int cur[2][256];
    __shared__ int sh[256];
    int t = threadIdx.x;
    int b = blockIdx.x;
    int half = t >> 7;
    int beg = b * BCAP, end = gcur[b];
    bins[0][t] = 0; bins[1][t] = 0;
    __syncthreads();
    for (int i = beg + t; i < end; i += 256)
        atomicAdd(&bins[half][part[i] & 255u], 1);
    __syncthreads();
    int d0 = bins[0][t];
    int deg = d0 + bins[1][t];
    int pdeg = (deg + 7) & ~7;
    sh[t] = pdeg;
    __syncthreads();
    for (int off = 1; off < 256; off <<= 1) {
        int x = (t >= off) ? sh[t - off] : 0;
        __syncthreads();
        sh[t] += x;
        __syncthreads();
    }
    int mybeg = b * BCAPP + (sh[t] - pdeg);
    int node = b * 256 + t;
    if (node < N) {
        rr[node] = make_int2(mybeg, mybeg + pdeg);
        dis[node] = rsqrtf((float)(deg + 1));
    }
    cur[0][t] = mybeg;
    cur[1][t] = mybeg + d0;
    __syncthreads();
    for (int i = beg + t; i < end; i += 256) {
        unsigned p = part[i];
        int pos = atomicAdd(&cur[half][p & 255u], 1);
        csr_src[pos] = (int)(p >> 8);
    }
    for (int k = deg; k < pdeg; ++k) csr_src[mybeg + k] = N;  // sentinels
}

// ---------------------------------------------------------------------------
// Fused aggregate + bias + tanh + LayerNorm + affine; split-hs gathers.
// (Byte-for-byte the R7 version that measured 120.4us total.)
// ---------------------------------------------------------------------------
template<bool BF16OUT>
__global__ __launch_bounds__(256) void k_agg_ln(const unsigned* __restrict__ hA32,
                                                const unsigned* __restrict__ hB32,
                                                const int2* __restrict__ rr,
                                                const int* __restrict__ csr_src,
                                                const float* __restrict__ dis,
                                                const float* __restrict__ b,
                                                const float* __restrict__ g,
                                                const float* __restrict__ be,
                                                void* __restrict__ outA,
                                                void* __restrict__ outB, int N) {
    int node = blockIdx.x * 8 + (threadIdx.x >> 5);
    int lane = threadIdx.x & 31;
    if (node >= N) return;

    float a0, a1, c0 = 0.f, c1 = 0.f;
    {
        unsigned v = hA32[(size_t)node * 32 + lane];
        a0 = blo(v); a1 = bhi(v);
        if (lane < 16) {
            unsigned uu = hB32[(size_t)node * 16 + lane];
            c0 = blo(uu); c1 = bhi(uu);
        }
    }

    int2 r = rr[node];
    int beg = r.x, end = r.y;
    int lsel = lane >> 4;
    int lb = lane & 15;
    for (int cb = beg; cb < end; cb += 32) {
        int m = min(32, end - cb);
        int e = cb + lane;
        int sreg = (e < end) ? csr_src[e] : (int)N;
        for (int j = 0; j < m; j += 8) {
            int s0 = __shfl(sreg, j, 32);
            int s1 = __shfl(sreg, j + 1, 32);
            int s2 = __shfl(sreg, j + 2, 32);
            int s3 = __shfl(sreg, j + 3, 32);
            int s4 = __shfl(sreg, j + 4, 32);
            int s5 = __shfl(sreg, j + 5, 32);
            int s6 = __shfl(sreg, j + 6, 32);
            int s7 = __shfl(sreg, j + 7, 32);
            int p0 = __shfl(sreg, j + lsel, 32);
            int p1 = __shfl(sreg, j + 2 + lsel, 32);
            int p2 = __shfl(sreg, j + 4 + lsel, 32);
            int p3 = __shfl(sreg, j + 6 + lsel, 32);
            unsigned v0 = hA32[s0 * 32 + lane];
            unsigned v1 = hA32[s1 * 32 + lane];
            unsigned v2 = hA32[s2 * 32 + lane];
            unsigned v3 = hA32[s3 * 32 + lane];
            unsigned v4 = hA32[s4 * 32 + lane];
            unsigned v5 = hA32[s5 * 32 + lane];
            unsigned v6 = hA32[s6 * 32 + lane];
            unsigned v7 = hA32[s7 * 32 + lane];
            unsigned w0 = hB32[p0 * 16 + lb];
            unsigned w1 = hB32[p1 * 16 + lb];
            unsigned w2 = hB32[p2 * 16 + lb];
            unsigned w3 = hB32[p3 * 16 + lb];
            a0 += blo(v0) + blo(v1) + blo(v2) + blo(v3)
                + blo(v4) + blo(v5) + blo(v6) + blo(v7);
            a1 += bhi(v0) + bhi(v1) + bhi(v2) + bhi(v3)
                + bhi(v4) + bhi(v5) + bhi(v6) + bhi(v7);
            c0 += blo(w0) + blo(w1) + blo(w2) + blo(w3);
            c1 += bhi(w0) + bhi(w1) + bhi(w2) + bhi(w3);
        }
    }

    c0 += __shfl_xor(c0, 16, 32);
    c1 += __shfl_xor(c1, 16, 32);

    float dn = dis[node];
    float2 b01 = ((const float2*)b)[lane];
    a0 = tanhf(fmaf(dn, a0, b01.x));
    a1 = tanhf(fmaf(dn, a1, b01.y));
    float s1 = a0 + a1;
    float s2 = a0 * a0 + a1 * a1;
    float a2 = 0.f, a3 = 0.f;
    if (lane < 16) {
        float2 b23 = ((const float2*)b)[32 + lane];
        a2 = tanhf(fmaf(dn, c0, b23.x));
        a3 = tanhf(fmaf(dn, c1, b23.y));
        s1 += a2 + a3;
        s2 += a2 * a2 + a3 * a3;
    }
    #pragma unroll
    for (int off = 16; off >= 1; off >>= 1) {
        s1 += __shfl_xor(s1, off, 32);
        s2 += __shfl_xor(s2, off, 32);
    }
    float mu = s1 * (1.f / 96.f);
    float var = s2 * (1.f / 96.f) - mu * mu;
    float inv = rsqrtf(var + LN_EPS);

    float2 g01 = ((const float2*)g)[lane];
    float2 e01 = ((const float2*)be)[lane];
    float r0 = (a0 - mu) * inv * g01.x + e01.x;
    float r1 = (a1 - mu) * inv * g01.y + e01.y;
    if (BF16OUT) {
        ((unsigned*)outA)[(size_t)node * 32 + lane] =
            ((unsigned)f2bf(r1) << 16) | (unsigned)f2bf(r0);
        if (lane < 16) {
            float2 g23 = ((const float2*)g)[32 + lane];
            float2 e23 = ((const float2*)be)[32 + lane];
            float r2 = (a2 - mu) * inv * g23.x + e23.x;
            float r3 = (a3 - mu) * inv * g23.y + e23.y;
            ((unsigned*)outB)[(size_t)node * 16 + lane] =
                ((unsigned)f2bf(r3) << 16) | (unsigned)f2bf(r2);
        }
    } else {
        float2* o2 = (float2*)((float*)outA + (size_t)node * D);
        o2[lane] = make_float2(r0, r1);
        if (lane < 16) {
            float2 g23 = ((const float2*)g)[32 + lane];
            float2 e23 = ((const float2*)be)[32 + lane];
            o2[32 + lane] = make_float2((a2 - mu) * inv * g23.x + e23.x,
                                        (a3 - mu) * inv * g23.y + e23.y);
        }
    }
}

// ---------------------------------------------------------------------------
extern "C" void kernel_launch(void* const* d_in, const int* in_sizes, int n_in,
                              void* d_out, int out_size, void* d_ws, size_t ws_size,
                              hipStream_t stream) {
    const float* x  = (const float*)d_in[0];
    const void*  eb = d_in[1];
    const float* W0 = (const float*)d_in[2];
    const float* b0 = (const float*)d_in[3];
    const float* g0 = (const float*)d_in[4];
    const float* be0 = (const float*)d_in[5];
    const float* W1 = (const float*)d_in[6];
    const float* b1 = (const float*)d_in[7];
    const float* g1 = (const float*)d_in[8];
    const float* be1 = (const float*)d_in[9];

    const int N = in_sizes[0] / D;
    const int E = in_sizes[1] / 2;
    const int NBUK = (N + 255) >> 8;
    const int NBLK = (E + CHUNK - 1) / CHUNK;

    auto al = [](size_t v) { return (v + 255) & ~(size_t)255; };
    char* w = (char*)d_ws;
    size_t off = 0;
    int* gcur = (int*)(w + off);          off = al(off + 256 * 4);
    int2* rr = (int2*)(w + off);          off = al(off + (size_t)N * 8);
    float* dis = (float*)(w + off);       off = al(off + (size_t)N * 4);
    int* csr_src = (int*)(w + off);       off = al(off + ((size_t)NBUK * BCAPP + 64) * 4);
    unsigned* part = (unsigned*)(w + off); off = al(off + ((size_t)NBUK * BCAP + BCAP) * 4);
    unsigned* hsA = (unsigned*)(w + off); off = al(off + ((size_t)N + 1) * 128);
    unsigned* hsB = (unsigned*)(w + off); off = al(off + ((size_t)N + 1) * 64);
    unsigned* h1A = (unsigned*)(w + off); off = al(off + (size_t)N * 128);
    unsigned* h1B = (unsigned*)(w + off); off = al(off + (size_t)N * 64);
    float* outf = (float*)d_out;

    const int nbG = (N + 63) / 64;
    const int nbA = (N + 7) / 8;

    k_init<<<1, 256, 0, stream>>>(gcur, hsA, hsB, N, NBUK);
    k_bfill<<<NBLK, 256, 0, stream>>>(eb, gcur, part, E);
    k_build<<<NBUK, 256, 0, stream>>>(part, gcur, rr, csr_src, dis, N);

    // Layer 1: MFMA GEMM (f32 in, W transposed-converted in staging) -> hs
    k_gemm_mfma<float, false><<<nbG, 256, 0, stream>>>(x, (const float*)nullptr, W0,
                                                       dis, (ushort_t*)hsA,
                                                       (ushort_t*)hsB, N, nullptr, 0);
    k_agg_ln<true><<<nbA, 256, 0, stream>>>(hsA, hsB, rr, csr_src, dis,
                                            b0, g0, be0, (void*)h1A, (void*)h1B, N);
    // Layer 2: MFMA GEMM (split bf16 in) -> hs ; agg -> d_out (f32)
    k_gemm_mfma<ushort_t, false><<<nbG, 256, 0, stream>>>((const ushort_t*)h1A,
                                                          (const ushort_t*)h1B, W1,
                                                          dis, (ushort_t*)hsA,
                                                          (ushort_t*)hsB, N, nullptr, 0);
    k_agg_ln<false><<<nbA, 256, 0, stream>>>(hsA, hsB, rr, csr_src, dis,
                                             b1, g1, be1, (void*)outf, nullptr, N);
}

// Round 11
// 120.380 us; speedup vs baseline: 1.1193x; 1.0539x over previous
//
#include <hip/hip_runtime.h>
#include <hip/hip_bf16.h>
#include <type_traits>

#define D 96
#define LN_EPS 1e-5f
#define CHUNK 1024        // edges per partition block
#define BCAP 8192         // per-bucket fixed capacity in part[] (mean 4096, +64 sigma)
#define BCAPP (BCAP + 1792) // per-bucket region in csr_src (pad-8 slack = 7*256)

typedef unsigned short ushort_t;
typedef __attribute__((ext_vector_type(8))) short short8;
typedef __attribute__((ext_vector_type(4))) float f32x4;

__device__ __forceinline__ ushort_t f2bf(float f) {
    unsigned u = __float_as_uint(f);
    u += 0x7FFF + ((u >> 16) & 1);          // round-to-nearest-even
    return (ushort_t)(u >> 16);
}
__device__ __forceinline__ float blo(unsigned v) {   // low bf16 -> f32
    return __uint_as_float(v << 16);
}
__device__ __forceinline__ float bhi(unsigned v) {   // high bf16 -> f32
    return __uint_as_float(v & 0xffff0000u);
}

// ---------------------------------------------------------------------------
// Init (block 0): edge dtype detect + gcur = b*BCAP + zero hs sentinel rows.
// Blocks 1..72: W0,W1 (f32 [k][c]) -> Wt0,Wt1 (bf16 transposed [c][k]).
// ---------------------------------------------------------------------------
__global__ __launch_bounds__(256) void k_init(const unsigned* __restrict__ w,
                                              int* __restrict__ flag,
                                              int* __restrict__ gcur,
                                              unsigned* __restrict__ hsA,
                                              unsigned* __restrict__ hsB, int N,
                                              int nbuk,
                                              const float* __restrict__ W0,
                                              const float* __restrict__ W1,
                                              ushort_t* __restrict__ Wt0,
                                              ushort_t* __restrict__ Wt1) {
    int t = threadIdx.x;
    if (blockIdx.x == 0) {
        __shared__ int anynz;
        if (t == 0) anynz = 0;
        __syncthreads();
        if ((t & 1) && w[t] != 0) anynz = 1;
        if (t < nbuk) gcur[t] = t * BCAP;
        if (t < 32) hsA[(size_t)N * 32 + t] = 0;   // sentinel row
        if (t < 16) hsB[(size_t)N * 16 + t] = 0;
        __syncthreads();
        if (t == 0) *flag = (anynz == 0) ? 1 : 0;
    } else {
        int idx = (blockIdx.x - 1) * 256 + t;   // < 18432
        int sel = idx / 9216, i = idx % 9216;
        int c = i / 96, k = i % 96;
        const float* W = sel ? W1 : W0;
        ushort_t* Wt = sel ? Wt1 : Wt0;
        Wt[c * 96 + k] = f2bf(W[k * 96 + c]);
    }
}

__device__ __forceinline__ int load_idx(const void* eb, int is64, long long pos) {
    if (is64) return (int)((const long long*)eb)[pos];
    return ((const int*)eb)[pos];
}

// ---------------------------------------------------------------------------
// Partition edges into fixed-capacity bucket regions (bucket = dst >> 8).
// Duplicated LDS hist/cursors (per wave-pair) halve same-bin serialization.
// ---------------------------------------------------------------------------
__global__ __launch_bounds__(256) void k_bfill(const void* __restrict__ eb,
                                               const int* __restrict__ flag,
                                               int* __restrict__ gcur,
                                               unsigned* __restrict__ part, int E) {
    __shared__ int hist[2][256];
    __shared__ int cur[2][256];
    int t = threadIdx.x;
    int half = t >> 7;
    hist[0][t] = 0; hist[1][t] = 0;
    __syncthreads();
    int is64 = *flag;
    long long base = (long long)blockIdx.x * CHUNK;
    int sv[CHUNK / 256];
    int dv[CHUNK / 256];
    #pragma unroll
    for (int i = 0; i < CHUNK / 256; ++i) {
        long long e = base + t + (long long)i * 256;
        if (e < E) {
            sv[i] = load_idx(eb, is64, e);
            dv[i] = load_idx(eb, is64, (long long)E + e);
            atomicAdd(&hist[half][dv[i] >> 8], 1);
        } else dv[i] = -1;
    }
    __syncthreads();
    int h0 = hist[0][t], tot = h0 + hist[1][t];
    int b0 = 0;
    if (tot > 0) b0 = atomicAdd(&gcur[t], tot);
    cur[0][t] = b0;
    cur[1][t] = b0 + h0;
    __syncthreads();
    #pragma unroll
    for (int i = 0; i < CHUNK / 256; ++i) {
        if (dv[i] >= 0) {
            int b = dv[i] >> 8;
            int pos = atomicAdd(&cur[half][b], 1);
            part[pos] = ((unsigned)sv[i] << 8) | (unsigned)(dv[i] & 255);
        }
    }
}

// ---------------------------------------------------------------------------
// Per-bucket CSR finalize, per-node padding to multiple of 8 (sentinel = N).
// Bucket b: part region [b*BCAP, gcur[b]); csr region starts at b*BCAPP.
// rr[node] = (rbeg, rend) packed.
// ---------------------------------------------------------------------------
__global__ __launch_bounds__(256) void k_build(const unsigned* __restrict__ part,
                                               const int* __restrict__ gcur,
                                               int2* __restrict__ rr,
                                               int* __restrict__ csr_src,
                                               float* __restrict__ dis,
                                               int N) {
    __shared__ int bins[2][256];
    __shared__ int cur[2][256];
    __shared__ int sh[256];
    int t = threadIdx.x;
    int b = blockIdx.x;
    int half = t >> 7;
    int beg = b * BCAP, end = gcur[b];
    bins[0][t] = 0; bins[1][t] = 0;
    __syncthreads();
    for (int i = beg + t; i < end; i += 256)
        atomicAdd(&bins[half][part[i] & 255u], 1);
    __syncthreads();
    int d0 = bins[0][t];
    int deg = d0 + bins[1][t];
    int pdeg = (deg + 7) & ~7;
    sh[t] = pdeg;
    __syncthreads();
    for (int off = 1; off < 256; off <<= 1) {
        int x = (t >= off) ? sh[t - off] : 0;
        __syncthreads();
        sh[t] += x;
        __syncthreads();
    }
    int mybeg = b * BCAPP + (sh[t] - pdeg);
    int node = b * 256 + t;
    if (node < N) {
        rr[node] = make_int2(mybeg, mybeg + pdeg);
        dis[node] = rsqrtf((float)(deg + 1));
    }
    cur[0][t] = mybeg;
    cur[1][t] = mybeg + d0;
    __syncthreads();
    for (int i = beg + t; i < end; i += 256) {
        unsigned p = part[i];
        int pos = atomicAdd(&cur[half][p & 255u], 1);
        csr_src[pos] = (int)(p >> 8);
    }
    for (int k = deg; k < pdeg; ++k) csr_src[mybeg + k] = N;  // sentinels
}

// ---------------------------------------------------------------------------
// MFMA GEMM: (HsA,HsB)[row] = bf16( dis[row] * (A[N,96] @ W[96,96]) ).
// A: f32 contiguous (layer 1, converted while staging) or split bf16
// (A0=[N][64], A1=[N][32], layer 2). Wt bf16 transposed. 64 rows/block,
// 4 waves, 16 rows/wave. mfma_f32_16x16x32_bf16, m89-verified C/D layout.
// LDS rows padded to 104 elems (208B) -> 2-way conflicts only (free).
// ---------------------------------------------------------------------------
template<typename T>
__global__ __launch_bounds__(256) void k_gemm_mfma(const T* __restrict__ A0,
                                                   const T* __restrict__ A1,
                                                   const ushort_t* __restrict__ Wt,
                                                   const float* __restrict__ dis,
                                                   ushort_t* __restrict__ HsA,
                                                   ushort_t* __restrict__ HsB, int N) {
    __shared__ ushort_t As[64][104];
    __shared__ ushort_t Bs[96][104];
    int t = threadIdx.x;
    int row0 = blockIdx.x * 64;

    if constexpr (std::is_same<T, float>::value) {
        const float4* X4 = (const float4*)A0;
        #pragma unroll
        for (int i = 0; i < 6; ++i) {             // 64x24 float4 = 1536 chunks
            int idx = t + i * 256;
            int r = idx / 24, c4 = idx % 24;
            float4 v = make_float4(0.f, 0.f, 0.f, 0.f);
            if (row0 + r < N) v = X4[(size_t)(row0 + r) * 24 + c4];
            ushort4 o;
            o.x = f2bf(v.x); o.y = f2bf(v.y); o.z = f2bf(v.z); o.w = f2bf(v.w);
            *(ushort4*)&As[r][c4 * 4] = o;
        }
    } else {
        #pragma unroll
        for (int i = 0; i < 3; ++i) {             // 64x12 short8 = 768 chunks
            int idx = t + i * 256;
            int r = idx / 12, c8 = idx % 12;
            short8 v = {0, 0, 0, 0, 0, 0, 0, 0};
            if (row0 + r < N) {
                if (c8 < 8) v = *(const short8*)(A0 + (size_t)(row0 + r) * 64 + c8 * 8);
                else        v = *(const short8*)(A1 + (size_t)(row0 + r) * 32 + (c8 - 8) * 8);
            }
            *(short8*)&As[r][c8 * 8] = v;
        }
    }
    #pragma unroll
    for (int i = 0; i < 5; ++i) {                 // 96x12 short8 = 1152 chunks
        int idx = t + i * 256;
        if (idx < 1152) {
            int r = idx / 12, c8 = idx % 12;
            *(short8*)&Bs[r][c8 * 8] = *(const short8*)(Wt + r * 96 + c8 * 8);
        }
    }
    __syncthreads();

    int w = t >> 6, l = t & 63;
    int lr = l & 15, lq = l >> 4;
    f32x4 acc[6];
    #pragma unroll
    for (int c = 0; c < 6; ++c) acc[c] = (f32x4){0.f, 0.f, 0.f, 0.f};

    #pragma unroll
    for (int q = 0; q < 3; ++q) {
        short8 af = *(const short8*)&As[w * 16 + lr][q * 32 + lq * 8];
        #pragma unroll
        for (int c = 0; c < 6; ++c) {
            short8 bf = *(const short8*)&Bs[c * 16 + lr][q * 32 + lq * 8];
            acc[c] = __builtin_amdgcn_mfma_f32_16x16x32_bf16(af, bf, acc[c], 0, 0, 0);
        }
    }

    int rbase = row0 + w * 16 + lq * 4;
    #pragma unroll
    for (int r = 0; r < 4; ++r) {
        int gr = rbase + r;
        if (gr < N) {
            float dr = dis[gr];
            ushort_t* oA = HsA + (size_t)gr * 64 + lr;
            ushort_t* oB = HsB + (size_t)gr * 32 + lr;
            #pragma unroll
            for (int c = 0; c < 4; ++c) oA[c * 16] = f2bf(dr * acc[c][r]);
            #pragma unroll
            for (int c = 4; c < 6; ++c) oB[(c - 4) * 16] = f2bf(dr * acc[c][r]);
        }
    }
}

// ---------------------------------------------------------------------------
// Fused aggregate + bias + tanh + LayerNorm + affine; split-hs gathers.
// 32-lane group per node. Lane l owns features {2l,2l+1} (hsA). hsB
// (features 64-95) is gathered two-edges-per-load: lanes 0-15 edge j,
// lanes 16-31 edge j+1, folded by shfl_xor(16) before the epilogue.
// Edge runs padded to x8 with sentinel row N (zeros); branch-free bursts.
// ---------------------------------------------------------------------------
template<bool BF16OUT>
__global__ __launch_bounds__(256) void k_agg_ln(const unsigned* __restrict__ hA32,
                                                const unsigned* __restrict__ hB32,
                                                const int2* __restrict__ rr,
                                                const int* __restrict__ csr_src,
                                                const float* __restrict__ dis,
                                                const float* __restrict__ b,
                                                const float* __restrict__ g,
                                                const float* __restrict__ be,
                                                void* __restrict__ outA,
                                                void* __restrict__ outB, int N) {
    int node = blockIdx.x * 8 + (threadIdx.x >> 5);
    int lane = threadIdx.x & 31;
    if (node >= N) return;

    float a0, a1, c0 = 0.f, c1 = 0.f;
    {
        unsigned v = hA32[(size_t)node * 32 + lane];
        a0 = blo(v); a1 = bhi(v);
        if (lane < 16) {
            unsigned uu = hB32[(size_t)node * 16 + lane];
            c0 = blo(uu); c1 = bhi(uu);
        }
    }

    int2 r = rr[node];
    int beg = r.x, end = r.y;
    int lsel = lane >> 4;      // 0 for lanes 0-15, 1 for 16-31
    int lb = lane & 15;
    for (int cb = beg; cb < end; cb += 32) {
        int m = min(32, end - cb);
        int e = cb + lane;
        int sreg = (e < end) ? csr_src[e] : (int)N;
        for (int j = 0; j < m; j += 8) {
            int s0 = __shfl(sreg, j, 32);
            int s1 = __shfl(sreg, j + 1, 32);
            int s2 = __shfl(sreg, j + 2, 32);
            int s3 = __shfl(sreg, j + 3, 32);
            int s4 = __shfl(sreg, j + 4, 32);
            int s5 = __shfl(sreg, j + 5, 32);
            int s6 = __shfl(sreg, j + 6, 32);
            int s7 = __shfl(sreg, j + 7, 32);
            int p0 = __shfl(sreg, j + lsel, 32);
            int p1 = __shfl(sreg, j + 2 + lsel, 32);
            int p2 = __shfl(sreg, j + 4 + lsel, 32);
            int p3 = __shfl(sreg, j + 6 + lsel, 32);
            unsigned v0 = hA32[s0 * 32 + lane];
            unsigned v1 = hA32[s1 * 32 + lane];
            unsigned v2 = hA32[s2 * 32 + lane];
            unsigned v3 = hA32[s3 * 32 + lane];
            unsigned v4 = hA32[s4 * 32 + lane];
            unsigned v5 = hA32[s5 * 32 + lane];
            unsigned v6 = hA32[s6 * 32 + lane];
            unsigned v7 = hA32[s7 * 32 + lane];
            unsigned w0 = hB32[p0 * 16 + lb];
            unsigned w1 = hB32[p1 * 16 + lb];
            unsigned w2 = hB32[p2 * 16 + lb];
            unsigned w3 = hB32[p3 * 16 + lb];
            a0 += blo(v0) + blo(v1) + blo(v2) + blo(v3)
                + blo(v4) + blo(v5) + blo(v6) + blo(v7);
            a1 += bhi(v0) + bhi(v1) + bhi(v2) + bhi(v3)
                + bhi(v4) + bhi(v5) + bhi(v6) + bhi(v7);
            c0 += blo(w0) + blo(w1) + blo(w2) + blo(w3);
            c1 += bhi(w0) + bhi(w1) + bhi(w2) + bhi(w3);
        }
    }

    // fold dual-edge hB accumulators (both halves end with the total)
    c0 += __shfl_xor(c0, 16, 32);
    c1 += __shfl_xor(c1, 16, 32);

    float dn = dis[node];
    float2 b01 = ((const float2*)b)[lane];
    a0 = tanhf(fmaf(dn, a0, b01.x));
    a1 = tanhf(fmaf(dn, a1, b01.y));
    float s1 = a0 + a1;
    float s2 = a0 * a0 + a1 * a1;
    float a2 = 0.f, a3 = 0.f;
    if (lane < 16) {
        float2 b23 = ((const float2*)b)[32 + lane];
        a2 = tanhf(fmaf(dn, c0, b23.x));
        a3 = tanhf(fmaf(dn, c1, b23.y));
        s1 += a2 + a3;
        s2 += a2 * a2 + a3 * a3;
    }
    #pragma unroll
    for (int off = 16; off >= 1; off >>= 1) {
        s1 += __shfl_xor(s1, off, 32);
        s2 += __shfl_xor(s2, off, 32);
    }
    float mu = s1 * (1.f / 96.f);
    float var = s2 * (1.f / 96.f) - mu * mu;
    float inv = rsqrtf(var + LN_EPS);

    float2 g01 = ((const float2*)g)[lane];
    float2 e01 = ((const float2*)be)[lane];
    float r0 = (a0 - mu) * inv * g01.x + e01.x;
    float r1 = (a1 - mu) * inv * g01.y + e01.y;
    if (BF16OUT) {
        ((unsigned*)outA)[(size_t)node * 32 + lane] =
            ((unsigned)f2bf(r1) << 16) | (unsigned)f2bf(r0);
        if (lane < 16) {
            float2 g23 = ((const float2*)g)[32 + lane];
            float2 e23 = ((const float2*)be)[32 + lane];
            float r2 = (a2 - mu) * inv * g23.x + e23.x;
            float r3 = (a3 - mu) * inv * g23.y + e23.y;
            ((unsigned*)outB)[(size_t)node * 16 + lane] =
                ((unsigned)f2bf(r3) << 16) | (unsigned)f2bf(r2);
        }
    } else {
        float2* o2 = (float2*)((float*)outA + (size_t)node * D);
        o2[lane] = make_float2(r0, r1);
        if (lane < 16) {
            float2 g23 = ((const float2*)g)[32 + lane];
            float2 e23 = ((const float2*)be)[32 + lane];
            o2[32 + lane] = make_float2((a2 - mu) * inv * g23.x + e23.x,
                                        (a3 - mu) * inv * g23.y + e23.y);
        }
    }
}

// ---------------------------------------------------------------------------
extern "C" void kernel_launch(void* const* d_in, const int* in_sizes, int n_in,
                              void* d_out, int out_size, void* d_ws, size_t ws_size,
                              hipStream_t stream) {
    const float* x  = (const float*)d_in[0];
    const void*  eb = d_in[1];
    const float* W0 = (const float*)d_in[2];
    const float* b0 = (const float*)d_in[3];
    const float* g0 = (const float*)d_in[4];
    const float* be0 = (const float*)d_in[5];
    const float* W1 = (const float*)d_in[6];
    const float* b1 = (const float*)d_in[7];
    const float* g1 = (const float*)d_in[8];
    const float* be1 = (const float*)d_in[9];

    const int N = in_sizes[0] / D;
    const int E = in_sizes[1] / 2;
    const int NBUK = (N + 255) >> 8;
    const int NBLK = (E + CHUNK - 1) / CHUNK;

    auto al = [](size_t v) { return (v + 255) & ~(size_t)255; };
    char* w = (char*)d_ws;
    size_t off = 0;
    int* flag = (int*)(w + off);          off = al(off + 4);
    int* gcur = (int*)(w + off);          off = al(off + 256 * 4);
    int2* rr = (int2*)(w + off);          off = al(off + (size_t)N * 8);
    float* dis = (float*)(w + off);       off = al(off + (size_t)N * 4);
    int* csr_src = (int*)(w + off);       off = al(off + ((size_t)NBUK * BCAPP + 64) * 4);
    unsigned* part = (unsigned*)(w + off); off = al(off + ((size_t)NBUK * BCAP + BCAP) * 4);
    unsigned* hsA = (unsigned*)(w + off); off = al(off + ((size_t)N + 1) * 128);
    unsigned* hsB = (unsigned*)(w + off); off = al(off + ((size_t)N + 1) * 64);
    unsigned* h1A = (unsigned*)(w + off); off = al(off + (size_t)N * 128);
    unsigned* h1B = (unsigned*)(w + off); off = al(off + (size_t)N * 64);
    ushort_t* Wt0 = (ushort_t*)(w + off); off = al(off + 9216 * 2);
    ushort_t* Wt1 = (ushort_t*)(w + off); off = al(off + 9216 * 2);
    float* outf = (float*)d_out;

    const int nbG = (N + 63) / 64;
    const int nbA = (N + 7) / 8;

    k_init<<<73, 256, 0, stream>>>((const unsigned*)eb, flag, gcur, hsA, hsB, N,
                                   NBUK, W0, W1, Wt0, Wt1);
    k_bfill<<<NBLK, 256, 0, stream>>>(eb, flag, gcur, part, E);
    k_build<<<NBUK, 256, 0, stream>>>(part, gcur, rr, csr_src, dis, N);

    // Layer 1: MFMA GEMM (f32 in, converts while staging) -> hsA/hsB ; agg -> h1A/h1B
    k_gemm_mfma<float><<<nbG, 256, 0, stream>>>(x, (const float*)nullptr, Wt0, dis,
                                                (ushort_t*)hsA, (ushort_t*)hsB, N);
    k_agg_ln<true><<<nbA, 256, 0, stream>>>(hsA, hsB, rr, csr_src, dis,
                                            b0, g0, be0, (void*)h1A, (void*)h1B, N);
    // Layer 2: MFMA GEMM (split bf16 in) -> hsA/hsB ; agg -> d_out (f32)
    k_gemm_mfma<ushort_t><<<nbG, 256, 0, stream>>>((const ushort_t*)h1A,
                                                   (const ushort_t*)h1B, Wt1, dis,
                                                   (ushort_t*)hsA, (ushort_t*)hsB, N);
    k_agg_ln<false><<<nbA, 256, 0, stream>>>(hsA, hsB, rr, csr_src, dis,
                                             b1, g1, be1, (void*)outf, nullptr, N);
}